// Round 1
// baseline (2895.266 us; speedup 1.0000x reference)
//
#include <hip/hip_runtime.h>

// Problem constants (B=4, C=256, H=W=64, N=4096, groups=8, heads=4, hd=64)
#define BATCH 4
#define CCH   256
#define NSP   4096          // H*W
#define NGRP  8
#define CPG   32            // C / groups
#define GRPSZ (CPG * NSP)   // 131072 elements per group
#define NHEAD 4
#define HD    64

// ---------------------------------------------------------------------------
// GroupNorm pass 1: partial sums. grid = 32 groups * 8 chunks, block = 256.
// ---------------------------------------------------------------------------
__global__ __launch_bounds__(256) void gn_partial(const float* __restrict__ x,
                                                  float* __restrict__ sums) {
    int chunk = blockIdx.x & 7;
    int bg    = blockIdx.x >> 3;            // b*8 + g
    const float* base = x + (size_t)bg * GRPSZ + (size_t)chunk * (GRPSZ / 8);
    int t = threadIdx.x;
    float s = 0.f, ss = 0.f;
#pragma unroll
    for (int i = 0; i < 16; ++i) {
        float4 v = *(const float4*)&base[(t + i * 256) * 4];
        s  += v.x + v.y + v.z + v.w;
        ss += v.x * v.x + v.y * v.y + v.z * v.z + v.w * v.w;
    }
    __shared__ float rs[256], rss[256];
    rs[t] = s; rss[t] = ss;
    __syncthreads();
    for (int off = 128; off > 0; off >>= 1) {
        if (t < off) { rs[t] += rs[t + off]; rss[t] += rss[t + off]; }
        __syncthreads();
    }
    if (t == 0) {
        sums[blockIdx.x * 2]     = rs[0];
        sums[blockIdx.x * 2 + 1] = rss[0];
    }
}

// ---------------------------------------------------------------------------
// GroupNorm pass 2: normalize + affine. grid = B*C = 1024 blocks, block = 256.
// ---------------------------------------------------------------------------
__global__ __launch_bounds__(256) void gn_apply(const float* __restrict__ x,
                                                const float* __restrict__ sums,
                                                const float* __restrict__ gw,
                                                const float* __restrict__ gb,
                                                float* __restrict__ h) {
    int bc = blockIdx.x;        // b*256 + c
    int c  = bc & 255;
    int bg = (bc >> 8) * 8 + (c >> 5);
    float s = 0.f, ss = 0.f;
#pragma unroll
    for (int i = 0; i < 8; ++i) {
        s  += sums[(bg * 8 + i) * 2];
        ss += sums[(bg * 8 + i) * 2 + 1];
    }
    const float invn = 1.f / (float)GRPSZ;
    float mean = s * invn;
    float var  = ss * invn - mean * mean;
    float inv  = rsqrtf(var + 1e-5f);
    float wc = gw[c] * inv;
    float bc_ = gb[c] - mean * wc;           // h = x*wc + bc_
    const float* xb = x + (size_t)bc * NSP;
    float*       hb = h + (size_t)bc * NSP;
    int t = threadIdx.x;
#pragma unroll
    for (int i = 0; i < 4; ++i) {
        float4 v = *(const float4*)&xb[(t + i * 256) * 4];
        v.x = v.x * wc + bc_;
        v.y = v.y * wc + bc_;
        v.z = v.z * wc + bc_;
        v.w = v.w * wc + bc_;
        *(float4*)&hb[(t + i * 256) * 4] = v;
    }
}

// ---------------------------------------------------------------------------
// 1x1-conv GEMM: Out[b][o][n] = sum_c W[o][c] * Hin[b][c][n] + bias[o] (+resid)
// grid = (NSP/64, M/64, B), block = 256. 64x64 tile, K-chunks of 16, 4x4 micro.
// ---------------------------------------------------------------------------
__global__ __launch_bounds__(256) void gemm1x1(const float* __restrict__ W,
                                               const float* __restrict__ Hin,
                                               const float* __restrict__ bias,
                                               const float* __restrict__ resid,
                                               float* __restrict__ Out,
                                               int M) {
    __shared__ float Ws[16][64];   // [k][o]
    __shared__ float Hs[16][64];   // [k][n]
    int b  = blockIdx.z;
    int o0 = blockIdx.y * 64;
    int n0 = blockIdx.x * 64;
    int t  = threadIdx.x;
    int tx = t & 15, ty = t >> 4;
    const float* Hb = Hin + (size_t)b * CCH * NSP;
    float acc[4][4] = {};
    for (int k0 = 0; k0 < CCH; k0 += 16) {
        {   // W tile: 64 o x 16 c
            int oo = t >> 2, cc = (t & 3) << 2;
            float4 wv = *(const float4*)&W[(size_t)(o0 + oo) * CCH + k0 + cc];
            Ws[cc + 0][oo] = wv.x;
            Ws[cc + 1][oo] = wv.y;
            Ws[cc + 2][oo] = wv.z;
            Ws[cc + 3][oo] = wv.w;
        }
        {   // H tile: 16 k x 64 n
            int kk = t >> 4, j = (t & 15) << 2;
            *(float4*)&Hs[kk][j] = *(const float4*)&Hb[(size_t)(k0 + kk) * NSP + n0 + j];
        }
        __syncthreads();
#pragma unroll
        for (int kk = 0; kk < 16; ++kk) {
            float a[4], bb[4];
            *(float4*)a  = *(const float4*)&Ws[kk][ty * 4];
            *(float4*)bb = *(const float4*)&Hs[kk][tx * 4];
#pragma unroll
            for (int i = 0; i < 4; ++i)
#pragma unroll
                for (int j = 0; j < 4; ++j)
                    acc[i][j] += a[i] * bb[j];
        }
        __syncthreads();
    }
#pragma unroll
    for (int i = 0; i < 4; ++i) {
        int o = o0 + ty * 4 + i;
        float bi = bias[o];
        size_t base = ((size_t)b * M + o) * NSP + n0 + tx * 4;
        float4 r = make_float4(acc[i][0] + bi, acc[i][1] + bi,
                               acc[i][2] + bi, acc[i][3] + bi);
        if (resid) {
            float4 rv = *(const float4*)&resid[base];
            r.x += rv.x; r.y += rv.y; r.z += rv.z; r.w += rv.w;
        }
        *(float4*)&Out[base] = r;
    }
}

// ---------------------------------------------------------------------------
// Flash attention (fp32). grid = (N/256, heads, B), block = 256.
// One query per thread; K/V staged in 64x64 LDS tiles; online softmax.
// ---------------------------------------------------------------------------
__global__ __launch_bounds__(256) void flash_attn(const float* __restrict__ qkv,
                                                  float* __restrict__ Oattn) {
    int t    = threadIdx.x;
    int q    = blockIdx.x * 256 + t;      // global query position (n)
    int head = blockIdx.y;
    int b    = blockIdx.z;
    const float* Q = qkv + (size_t)b * 3 * CCH * NSP + (size_t)(head * HD) * NSP;
    const float* K = Q + (size_t)CCH * NSP;
    const float* V = K + (size_t)CCH * NSP;

    __shared__ float Ks[HD][64];
    __shared__ float Vs[HD][64];

    float qreg[HD];
#pragma unroll
    for (int d = 0; d < HD; ++d) qreg[d] = Q[(size_t)d * NSP + q] * 0.125f;

    float m = -1e30f, l = 0.f;
    float o[HD];
#pragma unroll
    for (int d = 0; d < HD; ++d) o[d] = 0.f;

    for (int kt = 0; kt < NSP; kt += 64) {
        __syncthreads();
        {   // stage 64d x 64k tiles of K and V
            int f = t & 15, d0 = t >> 4;      // d0 in 0..15
#pragma unroll
            for (int r = 0; r < 4; ++r) {
                int d = d0 + r * 16;
                *(float4*)&Ks[d][f * 4] = *(const float4*)&K[(size_t)d * NSP + kt + f * 4];
                *(float4*)&Vs[d][f * 4] = *(const float4*)&V[(size_t)d * NSP + kt + f * 4];
            }
        }
        __syncthreads();
#pragma unroll 1
        for (int k4 = 0; k4 < 64; k4 += 4) {
            float s0 = 0.f, s1 = 0.f, s2 = 0.f, s3 = 0.f;
#pragma unroll
            for (int d = 0; d < HD; ++d) {
                float4 kv = *(const float4*)&Ks[d][k4];
                s0 += qreg[d] * kv.x;
                s1 += qreg[d] * kv.y;
                s2 += qreg[d] * kv.z;
                s3 += qreg[d] * kv.w;
            }
            float mt = fmaxf(fmaxf(s0, s1), fmaxf(s2, s3));
            if (mt > m) {                      // rare rescale
                float corr = __expf(m - mt);
                l *= corr;
#pragma unroll
                for (int d = 0; d < HD; ++d) o[d] *= corr;
                m = mt;
            }
            float p0 = __expf(s0 - m), p1 = __expf(s1 - m);
            float p2 = __expf(s2 - m), p3 = __expf(s3 - m);
            l += p0 + p1 + p2 + p3;
#pragma unroll
            for (int d = 0; d < HD; ++d) {
                float4 vv = *(const float4*)&Vs[d][k4];
                o[d] += p0 * vv.x + p1 * vv.y + p2 * vv.z + p3 * vv.w;
            }
        }
    }
    float inv = 1.f / l;
#pragma unroll
    for (int d = 0; d < HD; ++d)
        Oattn[(size_t)b * CCH * NSP + (size_t)(head * HD + d) * NSP + q] = o[d] * inv;
}

// ---------------------------------------------------------------------------
extern "C" void kernel_launch(void* const* d_in, const int* in_sizes, int n_in,
                              void* d_out, int out_size, void* d_ws, size_t ws_size,
                              hipStream_t stream) {
    const float* x    = (const float*)d_in[0];
    const float* nw   = (const float*)d_in[1];
    const float* nb   = (const float*)d_in[2];
    const float* qkvw = (const float*)d_in[3];
    const float* qkvb = (const float*)d_in[4];
    const float* pw   = (const float*)d_in[5];
    const float* pb   = (const float*)d_in[6];
    float* out = (float*)d_out;

    char* ws = (char*)d_ws;
    float* sums = (float*)ws;                                  // 512 floats
    float* h    = (float*)(ws + (1 << 16));                    // 16 MB (reused as attn out)
    float* qkv  = h + (size_t)BATCH * CCH * NSP;               // 48 MB
    float* aout = h;                                           // alias: h dead after QKV

    gn_partial<<<dim3(256), dim3(256), 0, stream>>>(x, sums);
    gn_apply<<<dim3(1024), dim3(256), 0, stream>>>(x, sums, nw, nb, h);
    gemm1x1<<<dim3(NSP / 64, 12, BATCH), dim3(256), 0, stream>>>(qkvw, h, qkvb, nullptr, qkv, 3 * CCH);
    flash_attn<<<dim3(NSP / 256, NHEAD, BATCH), dim3(256), 0, stream>>>(qkv, aout);
    gemm1x1<<<dim3(NSP / 64, 4, BATCH), dim3(256), 0, stream>>>(pw, aout, pb, x, out, CCH);
}

// Round 5
// 457.571 us; speedup vs baseline: 6.3275x; 6.3275x over previous
//
#include <hip/hip_runtime.h>

// Problem constants (B=4, C=256, H=W=64, N=4096, groups=8, heads=4, hd=64)
#define BATCH 4
#define CCH   256
#define NSP   4096          // H*W
#define NGRP  8
#define CPG   32            // C / groups
#define GRPSZ (CPG * NSP)   // 131072 elements per group
#define NHEAD 4
#define HD    64

typedef __attribute__((ext_vector_type(8))) short short8;   // 8 bf16 (4 VGPRs) MFMA A/B frag
typedef __attribute__((ext_vector_type(4))) float f32x4;    // MFMA C/D frag

// round-to-nearest-even f32 -> bf16 bits
__device__ __forceinline__ unsigned short f2b(float f) {
    unsigned u = __builtin_bit_cast(unsigned, f);
    unsigned r = u + 0x7FFFu + ((u >> 16) & 1u);
    return (unsigned short)(r >> 16);
}

// ---------------------------------------------------------------------------
// GroupNorm pass 1: partial sums. grid = 32 groups * 8 chunks, block = 256.
// ---------------------------------------------------------------------------
__global__ __launch_bounds__(256) void gn_partial(const float* __restrict__ x,
                                                  float* __restrict__ sums) {
    int chunk = blockIdx.x & 7;
    int bg    = blockIdx.x >> 3;            // b*8 + g
    const float* base = x + (size_t)bg * GRPSZ + (size_t)chunk * (GRPSZ / 8);
    int t = threadIdx.x;
    float s = 0.f, ss = 0.f;
#pragma unroll
    for (int i = 0; i < 16; ++i) {
        float4 v = *(const float4*)&base[(t + i * 256) * 4];
        s  += v.x + v.y + v.z + v.w;
        ss += v.x * v.x + v.y * v.y + v.z * v.z + v.w * v.w;
    }
    __shared__ float rs[256], rss[256];
    rs[t] = s; rss[t] = ss;
    __syncthreads();
    for (int off = 128; off > 0; off >>= 1) {
        if (t < off) { rs[t] += rs[t + off]; rss[t] += rss[t + off]; }
        __syncthreads();
    }
    if (t == 0) {
        sums[blockIdx.x * 2]     = rs[0];
        sums[blockIdx.x * 2 + 1] = rss[0];
    }
}

// ---------------------------------------------------------------------------
// GroupNorm pass 2: normalize + affine. grid = B*C = 1024 blocks, block = 256.
// ---------------------------------------------------------------------------
__global__ __launch_bounds__(256) void gn_apply(const float* __restrict__ x,
                                                const float* __restrict__ sums,
                                                const float* __restrict__ gw,
                                                const float* __restrict__ gb,
                                                float* __restrict__ h) {
    int bc = blockIdx.x;        // b*256 + c
    int c  = bc & 255;
    int bg = (bc >> 8) * 8 + (c >> 5);
    float s = 0.f, ss = 0.f;
#pragma unroll
    for (int i = 0; i < 8; ++i) {
        s  += sums[(bg * 8 + i) * 2];
        ss += sums[(bg * 8 + i) * 2 + 1];
    }
    const float invn = 1.f / (float)GRPSZ;
    float mean = s * invn;
    float var  = ss * invn - mean * mean;
    float inv  = rsqrtf(var + 1e-5f);
    float wc = gw[c] * inv;
    float bc_ = gb[c] - mean * wc;           // h = x*wc + bc_
    const float* xb = x + (size_t)bc * NSP;
    float*       hb = h + (size_t)bc * NSP;
    int t = threadIdx.x;
#pragma unroll
    for (int i = 0; i < 4; ++i) {
        float4 v = *(const float4*)&xb[(t + i * 256) * 4];
        v.x = v.x * wc + bc_;
        v.y = v.y * wc + bc_;
        v.z = v.z * wc + bc_;
        v.w = v.w * wc + bc_;
        *(float4*)&hb[(t + i * 256) * 4] = v;
    }
}

// ---------------------------------------------------------------------------
// 1x1-conv GEMM: Out[b][o][n] = sum_c W[o][c] * Hin[b][c][n] + bias[o] (+resid)
// grid = (NSP/64, M/64, B), block = 256. 64x64 tile, K-chunks of 16, 4x4 micro.
// ---------------------------------------------------------------------------
__global__ __launch_bounds__(256) void gemm1x1(const float* __restrict__ W,
                                               const float* __restrict__ Hin,
                                               const float* __restrict__ bias,
                                               const float* __restrict__ resid,
                                               float* __restrict__ Out,
                                               int M) {
    __shared__ float Ws[16][64];   // [k][o]
    __shared__ float Hs[16][64];   // [k][n]
    int b  = blockIdx.z;
    int o0 = blockIdx.y * 64;
    int n0 = blockIdx.x * 64;
    int t  = threadIdx.x;
    int tx = t & 15, ty = t >> 4;
    const float* Hb = Hin + (size_t)b * CCH * NSP;
    float acc[4][4] = {};
    for (int k0 = 0; k0 < CCH; k0 += 16) {
        {   // W tile: 64 o x 16 c
            int oo = t >> 2, cc = (t & 3) << 2;
            float4 wv = *(const float4*)&W[(size_t)(o0 + oo) * CCH + k0 + cc];
            Ws[cc + 0][oo] = wv.x;
            Ws[cc + 1][oo] = wv.y;
            Ws[cc + 2][oo] = wv.z;
            Ws[cc + 3][oo] = wv.w;
        }
        {   // H tile: 16 k x 64 n
            int kk = t >> 4, j = (t & 15) << 2;
            *(float4*)&Hs[kk][j] = *(const float4*)&Hb[(size_t)(k0 + kk) * NSP + n0 + j];
        }
        __syncthreads();
#pragma unroll
        for (int kk = 0; kk < 16; ++kk) {
            float a[4], bb[4];
            *(float4*)a  = *(const float4*)&Ws[kk][ty * 4];
            *(float4*)bb = *(const float4*)&Hs[kk][tx * 4];
#pragma unroll
            for (int i = 0; i < 4; ++i)
#pragma unroll
                for (int j = 0; j < 4; ++j)
                    acc[i][j] += a[i] * bb[j];
        }
        __syncthreads();
    }
#pragma unroll
    for (int i = 0; i < 4; ++i) {
        int o = o0 + ty * 4 + i;
        float bi = bias[o];
        size_t base = ((size_t)b * M + o) * NSP + n0 + tx * 4;
        float4 r = make_float4(acc[i][0] + bi, acc[i][1] + bi,
                               acc[i][2] + bi, acc[i][3] + bi);
        if (resid) {
            float4 rv = *(const float4*)&resid[base];
            r.x += rv.x; r.y += rv.y; r.z += rv.z; r.w += rv.w;
        }
        *(float4*)&Out[base] = r;
    }
}

// ---------------------------------------------------------------------------
// MFMA flash attention (bf16 inputs, fp32 accumulate).
// grid = (N/64, heads, B) = (64,4,4), block = 256 (4 waves x 16 queries).
// Per 64-key tile: stage K^T and V in LDS (bf16, XOR-swizzled), per wave
// 8 MFMA for S=Q^T K, wave-parallel online softmax, P via per-wave LDS,
// 8 MFMA for O += P V^T. O written coalesced via LDS transpose.
// Kt swizzle p(key)=(key^(key>>3))&7: write-side ~4-way (vs 8-way with key&7),
// read-side 2-way (free per m136).
// ---------------------------------------------------------------------------
__global__ __launch_bounds__(256, 4) void flash_mfma(const float* __restrict__ qkv,
                                                     float* __restrict__ Oattn) {
    __shared__ char smem[24576];
    unsigned short* Kt = (unsigned short*)smem;            // [64 key][64 d]  swizzled
    unsigned short* Vs = (unsigned short*)(smem + 8192);   // [64 d][64 key]  swizzled
    unsigned short* Pb = (unsigned short*)(smem + 16384);  // 4 waves x [16 q][64 k]

    const int t    = threadIdx.x;
    const int lane = t & 63;
    const int wid  = t >> 6;
    const int g    = lane >> 4;     // 16-lane group 0..3
    const int cl   = lane & 15;

    const int head = blockIdx.y, b = blockIdx.z;
    const int q0b  = blockIdx.x * 64;
    const float* Q = qkv + (size_t)b * 3 * CCH * NSP + (size_t)head * HD * NSP;
    const float* K = Q + (size_t)CCH * NSP;
    const float* V = K + (size_t)CCH * NSP;

    // Q A-fragments: lane holds Q^T[q][d-slice], q = q0b + wid*16 + cl
    const int qg = q0b + wid * 16 + cl;
    short8 qf[2];
#pragma unroll
    for (int h = 0; h < 2; ++h)
#pragma unroll
        for (int j = 0; j < 8; ++j) {
            int d = h * 32 + g * 8 + j;
            qf[h][j] = (short)f2b(Q[(size_t)d * NSP + qg] * 0.125f);
        }

    f32x4 o_acc[4];                 // O[q][d], 4 d-subtiles
#pragma unroll
    for (int ds = 0; ds < 4; ++ds) o_acc[ds] = (f32x4){0.f, 0.f, 0.f, 0.f};
    float m[4], l[4];
#pragma unroll
    for (int r = 0; r < 4; ++r) { m[r] = -1e30f; l[r] = 0.f; }

    const int kq4 = (t & 15) * 4;   // staging: 4 keys
    const int dd  = t >> 4;         // staging: d row (0..15, x4 passes)

    for (int kt = 0; kt < NSP; kt += 64) {
        __syncthreads();
        // ---- stage K (transposed -> Kt[key][d]) and V (-> Vs[d][key]) as bf16
#pragma unroll
        for (int p = 0; p < 4; ++p) {
            int d = dd + p * 16;
            const float4 kv = *(const float4*)&K[(size_t)d * NSP + kt + kq4];
            const float4 vv = *(const float4*)&V[(size_t)d * NSP + kt + kq4];
            unsigned short kb[4] = {f2b(kv.x), f2b(kv.y), f2b(kv.z), f2b(kv.w)};
#pragma unroll
            for (int i = 0; i < 4; ++i) {
                int key = kq4 + i;
                int sw = ((key ^ (key >> 3)) & 7) << 3;
                Kt[key * 64 + (d ^ sw)] = kb[i];
            }
            ushort4 vb = {f2b(vv.x), f2b(vv.y), f2b(vv.z), f2b(vv.w)};
            *(ushort4*)&Vs[d * 64 + (kq4 ^ ((d & 7) << 3))] = vb;
        }
        __syncthreads();

        // ---- S = Q^T K : 4 key-subtiles x 2 K-halves
        f32x4 accs[4];
#pragma unroll
        for (int s = 0; s < 4; ++s) {
            f32x4 a = (f32x4){0.f, 0.f, 0.f, 0.f};
            int row = s * 16 + cl;      // key row in Kt
            int sw  = ((row ^ (row >> 3)) & 7) << 3;
#pragma unroll
            for (int h = 0; h < 2; ++h) {
                short8 kf = *(short8*)&Kt[row * 64 + ((h * 32 + g * 8) ^ sw)];
                a = __builtin_amdgcn_mfma_f32_16x16x32_bf16(qf[h], kf, a, 0, 0, 0);
            }
            accs[s] = a;
        }

        // ---- online softmax; reg r = query row (g*4+r), cols spread over 16 lanes
        unsigned short pb16[4][4];      // [r][s]
#pragma unroll
        for (int r = 0; r < 4; ++r) {
            float rm = fmaxf(fmaxf(accs[0][r], accs[1][r]), fmaxf(accs[2][r], accs[3][r]));
#pragma unroll
            for (int mask = 1; mask < 16; mask <<= 1)
                rm = fmaxf(rm, __shfl_xor(rm, mask));
            float mn   = fmaxf(m[r], rm);
            float corr = __expf(m[r] - mn);
            m[r] = mn;
            l[r] *= corr;
            o_acc[0][r] *= corr; o_acc[1][r] *= corr;
            o_acc[2][r] *= corr; o_acc[3][r] *= corr;
            float ps = 0.f;
#pragma unroll
            for (int s = 0; s < 4; ++s) {
                float p = __expf(accs[s][r] - mn);
                ps += p;
                pb16[r][s] = f2b(p);
            }
            l[r] += ps;                 // lane-partial; cross-lane reduce at end
        }

        // ---- P -> per-wave LDS (bf16, swizzled), then PV MFMAs
        unsigned short* Pw = Pb + wid * 16 * 64;
#pragma unroll
        for (int r = 0; r < 4; ++r) {
            int row = g * 4 + r;
#pragma unroll
            for (int s = 0; s < 4; ++s) {
                int col = s * 16 + cl;
                Pw[row * 64 + (col ^ ((row & 7) << 3))] = pb16[r][s];
            }
        }
        short8 pf[2];
#pragma unroll
        for (int h2 = 0; h2 < 2; ++h2)
            pf[h2] = *(short8*)&Pw[cl * 64 + ((h2 * 32 + g * 8) ^ ((cl & 7) << 3))];
#pragma unroll
        for (int ds = 0; ds < 4; ++ds) {
            int vrow = ds * 16 + cl;    // vrow&7 == cl&7
#pragma unroll
            for (int h2 = 0; h2 < 2; ++h2) {
                short8 vf = *(short8*)&Vs[vrow * 64 + ((h2 * 32 + g * 8) ^ ((cl & 7) << 3))];
                o_acc[ds] = __builtin_amdgcn_mfma_f32_16x16x32_bf16(pf[h2], vf, o_acc[ds], 0, 0, 0);
            }
        }
    }

    // ---- finalize: reduce l across the 16 cols, normalize, coalesced write-out
    float inv[4];
#pragma unroll
    for (int r = 0; r < 4; ++r) {
        float s = l[r];
#pragma unroll
        for (int mask = 1; mask < 16; mask <<= 1) s += __shfl_xor(s, mask);
        inv[r] = 1.f / s;
    }
    __syncthreads();                    // everyone done with Kt/Vs/Pb
    float* Of = (float*)smem + wid * 1088;   // per-wave [64 d][stride 17] f32
#pragma unroll
    for (int ds = 0; ds < 4; ++ds)
#pragma unroll
        for (int r = 0; r < 4; ++r)
            Of[(ds * 16 + cl) * 17 + g * 4 + r] = o_acc[ds][r] * inv[r];
    __syncthreads();
    {
        int q4 = (t & 15) * 4;          // 4 consecutive queries
        const float* Ofw = (float*)smem + (q4 >> 4) * 1088;
        int qw = q4 & 15;
#pragma unroll
        for (int p = 0; p < 4; ++p) {
            int d = (t >> 4) + p * 16;
            float4 v;
            v.x = Ofw[d * 17 + qw + 0];
            v.y = Ofw[d * 17 + qw + 1];
            v.z = Ofw[d * 17 + qw + 2];
            v.w = Ofw[d * 17 + qw + 3];
            *(float4*)&Oattn[((size_t)b * CCH + head * HD + d) * NSP + q0b + q4] = v;
        }
    }
}

// ---------------------------------------------------------------------------
extern "C" void kernel_launch(void* const* d_in, const int* in_sizes, int n_in,
                              void* d_out, int out_size, void* d_ws, size_t ws_size,
                              hipStream_t stream) {
    const float* x    = (const float*)d_in[0];
    const float* nw   = (const float*)d_in[1];
    const float* nb   = (const float*)d_in[2];
    const float* qkvw = (const float*)d_in[3];
    const float* qkvb = (const float*)d_in[4];
    const float* pw   = (const float*)d_in[5];
    const float* pb   = (const float*)d_in[6];
    float* out = (float*)d_out;

    char* ws = (char*)d_ws;
    float* sums = (float*)ws;                                  // 512 floats
    float* h    = (float*)(ws + (1 << 16));                    // 16 MB (reused as attn out)
    float* qkv  = h + (size_t)BATCH * CCH * NSP;               // 48 MB
    float* aout = h;                                           // alias: h dead after QKV

    gn_partial<<<dim3(256), dim3(256), 0, stream>>>(x, sums);
    gn_apply<<<dim3(1024), dim3(256), 0, stream>>>(x, sums, nw, nb, h);
    gemm1x1<<<dim3(NSP / 64, 12, BATCH), dim3(256), 0, stream>>>(qkvw, h, qkvb, nullptr, qkv, 3 * CCH);
    flash_mfma<<<dim3(NSP / 64, NHEAD, BATCH), dim3(256), 0, stream>>>(qkv, aout);
    gemm1x1<<<dim3(NSP / 64, 4, BATCH), dim3(256), 0, stream>>>(pw, aout, pb, x, out, CCH);
}

// Round 6
// 373.618 us; speedup vs baseline: 7.7493x; 1.2247x over previous
//
#include <hip/hip_runtime.h>

// Problem constants (B=4, C=256, H=W=64, N=4096, groups=8, heads=4, hd=64)
#define BATCH 4
#define CCH   256
#define NSP   4096          // H*W
#define NGRP  8
#define CPG   32            // C / groups
#define GRPSZ (CPG * NSP)   // 131072 elements per group
#define NHEAD 4
#define HD    64

typedef __attribute__((ext_vector_type(8))) short short8;            // 8 bf16 MFMA A/B frag
typedef __attribute__((ext_vector_type(8))) unsigned short ushort8_t;
typedef __attribute__((ext_vector_type(4))) float f32x4;             // MFMA C/D frag

// round-to-nearest-even f32 -> bf16 bits
__device__ __forceinline__ unsigned short f2b(float f) {
    unsigned u = __builtin_bit_cast(unsigned, f);
    unsigned r = u + 0x7FFFu + ((u >> 16) & 1u);
    return (unsigned short)(r >> 16);
}

// ---------------------------------------------------------------------------
// GroupNorm pass 1: partial sums. grid = 32 groups * 8 chunks, block = 256.
// ---------------------------------------------------------------------------
__global__ __launch_bounds__(256) void gn_partial(const float* __restrict__ x,
                                                  float* __restrict__ sums) {
    int chunk = blockIdx.x & 7;
    int bg    = blockIdx.x >> 3;            // b*8 + g
    const float* base = x + (size_t)bg * GRPSZ + (size_t)chunk * (GRPSZ / 8);
    int t = threadIdx.x;
    float s = 0.f, ss = 0.f;
#pragma unroll
    for (int i = 0; i < 16; ++i) {
        float4 v = *(const float4*)&base[(t + i * 256) * 4];
        s  += v.x + v.y + v.z + v.w;
        ss += v.x * v.x + v.y * v.y + v.z * v.z + v.w * v.w;
    }
    __shared__ float rs[256], rss[256];
    rs[t] = s; rss[t] = ss;
    __syncthreads();
    for (int off = 128; off > 0; off >>= 1) {
        if (t < off) { rs[t] += rs[t + off]; rss[t] += rss[t + off]; }
        __syncthreads();
    }
    if (t == 0) {
        sums[blockIdx.x * 2]     = rs[0];
        sums[blockIdx.x * 2 + 1] = rss[0];
    }
}

// ---------------------------------------------------------------------------
// GroupNorm pass 2: normalize + affine. grid = B*C = 1024 blocks, block = 256.
// ---------------------------------------------------------------------------
__global__ __launch_bounds__(256) void gn_apply(const float* __restrict__ x,
                                                const float* __restrict__ sums,
                                                const float* __restrict__ gw,
                                                const float* __restrict__ gb,
                                                float* __restrict__ h) {
    int bc = blockIdx.x;        // b*256 + c
    int c  = bc & 255;
    int bg = (bc >> 8) * 8 + (c >> 5);
    float s = 0.f, ss = 0.f;
#pragma unroll
    for (int i = 0; i < 8; ++i) {
        s  += sums[(bg * 8 + i) * 2];
        ss += sums[(bg * 8 + i) * 2 + 1];
    }
    const float invn = 1.f / (float)GRPSZ;
    float mean = s * invn;
    float var  = ss * invn - mean * mean;
    float inv  = rsqrtf(var + 1e-5f);
    float wc = gw[c] * inv;
    float bc_ = gb[c] - mean * wc;           // h = x*wc + bc_
    const float* xb = x + (size_t)bc * NSP;
    float*       hb = h + (size_t)bc * NSP;
    int t = threadIdx.x;
#pragma unroll
    for (int i = 0; i < 4; ++i) {
        float4 v = *(const float4*)&xb[(t + i * 256) * 4];
        v.x = v.x * wc + bc_;
        v.y = v.y * wc + bc_;
        v.z = v.z * wc + bc_;
        v.w = v.w * wc + bc_;
        *(float4*)&hb[(t + i * 256) * 4] = v;
    }
}

// ---------------------------------------------------------------------------
// QKV GEMM with bf16 pack epilogue. grid = (64 n-tiles, 12 o-tiles, B).
// o-tile y: sect = y>>2 (0=Q,1=K,2=V), head = y&3 — each block's 64x64 (o,n)
// tile is exactly one (head, key-tile). Epilogue writes bf16 directly in the
// layout flash_mfma consumes (no fp32 qkv array):
//   Q: [q][d] scaled by hd^-0.5;  K: [key][d ^ swK(key)];  V: [d][key ^ swV(d)]
// ---------------------------------------------------------------------------
__global__ __launch_bounds__(256) void gemm_qkv(const float* __restrict__ W,
                                                const float* __restrict__ Hin,
                                                const float* __restrict__ bias,
                                                unsigned short* __restrict__ Qbf,
                                                unsigned short* __restrict__ Ktbf,
                                                unsigned short* __restrict__ Vbf) {
    __shared__ float Ws[16][64];   // [k][o]
    __shared__ float Hs[16][64];   // [k][n]
    int b  = blockIdx.z;
    int o0 = blockIdx.y * 64;
    int n0 = blockIdx.x * 64;
    int t  = threadIdx.x;
    int tx = t & 15, ty = t >> 4;
    const float* Hb = Hin + (size_t)b * CCH * NSP;
    float acc[4][4] = {};
    for (int k0 = 0; k0 < CCH; k0 += 16) {
        {   // W tile: 64 o x 16 c
            int oo = t >> 2, cc = (t & 3) << 2;
            float4 wv = *(const float4*)&W[(size_t)(o0 + oo) * CCH + k0 + cc];
            Ws[cc + 0][oo] = wv.x;
            Ws[cc + 1][oo] = wv.y;
            Ws[cc + 2][oo] = wv.z;
            Ws[cc + 3][oo] = wv.w;
        }
        {   // H tile: 16 k x 64 n
            int kk = t >> 4, j = (t & 15) << 2;
            *(float4*)&Hs[kk][j] = *(const float4*)&Hb[(size_t)(k0 + kk) * NSP + n0 + j];
        }
        __syncthreads();
#pragma unroll
        for (int kk = 0; kk < 16; ++kk) {
            float a[4], bb[4];
            *(float4*)a  = *(const float4*)&Ws[kk][ty * 4];
            *(float4*)bb = *(const float4*)&Hs[kk][tx * 4];
#pragma unroll
            for (int i = 0; i < 4; ++i)
#pragma unroll
                for (int j = 0; j < 4; ++j)
                    acc[i][j] += a[i] * bb[j];
        }
        __syncthreads();
    }
    // ---- pack epilogue
    int sect = blockIdx.y >> 2, head = blockIdx.y & 3;
    size_t tilebase = (((size_t)b * NHEAD + head) * 64 + blockIdx.x) * 4096;
    float bi[4];
#pragma unroll
    for (int i = 0; i < 4; ++i) bi[i] = bias[o0 + ty * 4 + i];
    if (sect == 0) {            // Q: transpose to [q][d], scale
        unsigned short* Qt = Qbf + tilebase;
#pragma unroll
        for (int j = 0; j < 4; ++j) {
            int q = tx * 4 + j;
            ushort4 w = { f2b((acc[0][j] + bi[0]) * 0.125f), f2b((acc[1][j] + bi[1]) * 0.125f),
                          f2b((acc[2][j] + bi[2]) * 0.125f), f2b((acc[3][j] + bi[3]) * 0.125f) };
            *(ushort4*)&Qt[q * 64 + ty * 4] = w;
        }
    } else if (sect == 1) {     // K: transpose to [key][d ^ sw(key)]
        unsigned short* Kt = Ktbf + tilebase;
#pragma unroll
        for (int j = 0; j < 4; ++j) {
            int key = tx * 4 + j;
            int sw = ((key ^ (key >> 3)) & 7) << 3;
            ushort4 w = { f2b(acc[0][j] + bi[0]), f2b(acc[1][j] + bi[1]),
                          f2b(acc[2][j] + bi[2]), f2b(acc[3][j] + bi[3]) };
            *(ushort4*)&Kt[key * 64 + ((ty * 4) ^ sw)] = w;
        }
    } else {                    // V: keep [d][key ^ sw(d)]
        unsigned short* Vt = Vbf + tilebase;
#pragma unroll
        for (int i = 0; i < 4; ++i) {
            int d = ty * 4 + i;
            ushort4 w = { f2b(acc[i][0] + bi[i]), f2b(acc[i][1] + bi[i]),
                          f2b(acc[i][2] + bi[i]), f2b(acc[i][3] + bi[i]) };
            *(ushort4*)&Vt[d * 64 + ((tx * 4) ^ ((d & 7) << 3))] = w;
        }
    }
}

// ---------------------------------------------------------------------------
// 1x1-conv GEMM fp32 (proj): Out = W*Hin + bias + resid.
// ---------------------------------------------------------------------------
__global__ __launch_bounds__(256) void gemm1x1(const float* __restrict__ W,
                                               const float* __restrict__ Hin,
                                               const float* __restrict__ bias,
                                               const float* __restrict__ resid,
                                               float* __restrict__ Out,
                                               int M) {
    __shared__ float Ws[16][64];   // [k][o]
    __shared__ float Hs[16][64];   // [k][n]
    int b  = blockIdx.z;
    int o0 = blockIdx.y * 64;
    int n0 = blockIdx.x * 64;
    int t  = threadIdx.x;
    int tx = t & 15, ty = t >> 4;
    const float* Hb = Hin + (size_t)b * CCH * NSP;
    float acc[4][4] = {};
    for (int k0 = 0; k0 < CCH; k0 += 16) {
        {
            int oo = t >> 2, cc = (t & 3) << 2;
            float4 wv = *(const float4*)&W[(size_t)(o0 + oo) * CCH + k0 + cc];
            Ws[cc + 0][oo] = wv.x;
            Ws[cc + 1][oo] = wv.y;
            Ws[cc + 2][oo] = wv.z;
            Ws[cc + 3][oo] = wv.w;
        }
        {
            int kk = t >> 4, j = (t & 15) << 2;
            *(float4*)&Hs[kk][j] = *(const float4*)&Hb[(size_t)(k0 + kk) * NSP + n0 + j];
        }
        __syncthreads();
#pragma unroll
        for (int kk = 0; kk < 16; ++kk) {
            float a[4], bb[4];
            *(float4*)a  = *(const float4*)&Ws[kk][ty * 4];
            *(float4*)bb = *(const float4*)&Hs[kk][tx * 4];
#pragma unroll
            for (int i = 0; i < 4; ++i)
#pragma unroll
                for (int j = 0; j < 4; ++j)
                    acc[i][j] += a[i] * bb[j];
        }
        __syncthreads();
    }
#pragma unroll
    for (int i = 0; i < 4; ++i) {
        int o = o0 + ty * 4 + i;
        float bi = bias[o];
        size_t base = ((size_t)b * M + o) * NSP + n0 + tx * 4;
        float4 r = make_float4(acc[i][0] + bi, acc[i][1] + bi,
                               acc[i][2] + bi, acc[i][3] + bi);
        if (resid) {
            float4 rv = *(const float4*)&resid[base];
            r.x += rv.x; r.y += rv.y; r.z += rv.z; r.w += rv.w;
        }
        *(float4*)&Out[base] = r;
    }
}

// ---------------------------------------------------------------------------
// MFMA flash attention v2 (pre-packed bf16 Q/K/V; fp32 accumulate).
// grid = (N/64, heads, B) = (64,4,4), block = 256 (4 waves x 16 queries).
// Staging is now a straight 16 KB linear copy (dwordx4 -> ds_write_b128),
// conversions/transposes/swizzles all pre-done by gemm_qkv's epilogue.
// ---------------------------------------------------------------------------
__global__ __launch_bounds__(256, 4) void flash_mfma(const unsigned short* __restrict__ Qbf,
                                                     const unsigned short* __restrict__ Ktbf,
                                                     const unsigned short* __restrict__ Vbf,
                                                     float* __restrict__ Oattn) {
    __shared__ char smem[24576];
    unsigned short* Kt = (unsigned short*)smem;            // [64 key][64 d]  swizzled
    unsigned short* Vs = (unsigned short*)(smem + 8192);   // [64 d][64 key]  swizzled
    unsigned short* Pb = (unsigned short*)(smem + 16384);  // 4 waves x [16 q][64 k]

    const int t    = threadIdx.x;
    const int lane = t & 63;
    const int wid  = t >> 6;
    const int g    = lane >> 4;     // 16-lane group 0..3
    const int cl   = lane & 15;

    const int head = blockIdx.y, b = blockIdx.z;
    const int bh   = b * NHEAD + head;

    // Q A-fragments: straight vector loads from packed [q][d] (pre-scaled bf16)
    const unsigned short* Qt = Qbf + (((size_t)bh * 64 + blockIdx.x) * 4096);
    short8 qf[2];
    qf[0] = *(const short8*)&Qt[(wid * 16 + cl) * 64 + g * 8];
    qf[1] = *(const short8*)&Qt[(wid * 16 + cl) * 64 + 32 + g * 8];

    f32x4 o_acc[4];                 // O[q][d], 4 d-subtiles
#pragma unroll
    for (int ds = 0; ds < 4; ++ds) o_acc[ds] = (f32x4){0.f, 0.f, 0.f, 0.f};
    float m[4], l[4];
#pragma unroll
    for (int r = 0; r < 4; ++r) { m[r] = -1e30f; l[r] = 0.f; }

    for (int tile = 0; tile < 64; ++tile) {
        __syncthreads();
        // ---- stage: linear 8 KB copies of pre-packed K-tile and V-tile
        {
            const ushort8_t* kg = (const ushort8_t*)(Ktbf + (((size_t)bh * 64 + tile) * 4096));
            const ushort8_t* vg = (const ushort8_t*)(Vbf  + (((size_t)bh * 64 + tile) * 4096));
            ushort8_t* kl = (ushort8_t*)Kt;
            ushort8_t* vl = (ushort8_t*)Vs;
            kl[t]       = kg[t];
            kl[t + 256] = kg[t + 256];
            vl[t]       = vg[t];
            vl[t + 256] = vg[t + 256];
        }
        __syncthreads();

        // ---- S = Q^T K : 4 key-subtiles x 2 K-halves
        f32x4 accs[4];
#pragma unroll
        for (int s = 0; s < 4; ++s) {
            f32x4 a = (f32x4){0.f, 0.f, 0.f, 0.f};
            int row = s * 16 + cl;      // key row in Kt
            int sw  = ((row ^ (row >> 3)) & 7) << 3;
#pragma unroll
            for (int h = 0; h < 2; ++h) {
                short8 kf = *(short8*)&Kt[row * 64 + ((h * 32 + g * 8) ^ sw)];
                a = __builtin_amdgcn_mfma_f32_16x16x32_bf16(qf[h], kf, a, 0, 0, 0);
            }
            accs[s] = a;
        }

        // ---- online softmax; reg r = query row (g*4+r), cols spread over 16 lanes
        unsigned short pb16[4][4];      // [r][s]
#pragma unroll
        for (int r = 0; r < 4; ++r) {
            float rm = fmaxf(fmaxf(accs[0][r], accs[1][r]), fmaxf(accs[2][r], accs[3][r]));
#pragma unroll
            for (int mask = 1; mask < 16; mask <<= 1)
                rm = fmaxf(rm, __shfl_xor(rm, mask));
            float mn   = fmaxf(m[r], rm);
            float corr = __expf(m[r] - mn);
            m[r] = mn;
            l[r] *= corr;
            o_acc[0][r] *= corr; o_acc[1][r] *= corr;
            o_acc[2][r] *= corr; o_acc[3][r] *= corr;
            float ps = 0.f;
#pragma unroll
            for (int s = 0; s < 4; ++s) {
                float p = __expf(accs[s][r] - mn);
                ps += p;
                pb16[r][s] = f2b(p);
            }
            l[r] += ps;                 // lane-partial; cross-lane reduce at end
        }

        // ---- P -> per-wave LDS (bf16, swizzled), then PV MFMAs
        unsigned short* Pw = Pb + wid * 16 * 64;
#pragma unroll
        for (int r = 0; r < 4; ++r) {
            int row = g * 4 + r;
#pragma unroll
            for (int s = 0; s < 4; ++s) {
                int col = s * 16 + cl;
                Pw[row * 64 + (col ^ ((row & 7) << 3))] = pb16[r][s];
            }
        }
        short8 pf[2];
#pragma unroll
        for (int h2 = 0; h2 < 2; ++h2)
            pf[h2] = *(short8*)&Pw[cl * 64 + ((h2 * 32 + g * 8) ^ ((cl & 7) << 3))];
#pragma unroll
        for (int ds = 0; ds < 4; ++ds) {
            int vrow = ds * 16 + cl;    // vrow&7 == cl&7
#pragma unroll
            for (int h2 = 0; h2 < 2; ++h2) {
                short8 vf = *(short8*)&Vs[vrow * 64 + ((h2 * 32 + g * 8) ^ ((cl & 7) << 3))];
                o_acc[ds] = __builtin_amdgcn_mfma_f32_16x16x32_bf16(pf[h2], vf, o_acc[ds], 0, 0, 0);
            }
        }
    }

    // ---- finalize: reduce l across the 16 cols, normalize, coalesced write-out
    float inv[4];
#pragma unroll
    for (int r = 0; r < 4; ++r) {
        float s = l[r];
#pragma unroll
        for (int mask = 1; mask < 16; mask <<= 1) s += __shfl_xor(s, mask);
        inv[r] = 1.f / s;
    }
    __syncthreads();                    // everyone done with Kt/Vs/Pb
    float* Of = (float*)smem + wid * 1088;   // per-wave [64 d][stride 17] f32
#pragma unroll
    for (int ds = 0; ds < 4; ++ds)
#pragma unroll
        for (int r = 0; r < 4; ++r)
            Of[(ds * 16 + cl) * 17 + g * 4 + r] = o_acc[ds][r] * inv[r];
    __syncthreads();
    {
        int q4 = (t & 15) * 4;          // 4 consecutive queries
        const float* Ofw = (float*)smem + (q4 >> 4) * 1088;
        int qw = q4 & 15;
#pragma unroll
        for (int p = 0; p < 4; ++p) {
            int d = (t >> 4) + p * 16;
            float4 v;
            v.x = Ofw[d * 17 + qw + 0];
            v.y = Ofw[d * 17 + qw + 1];
            v.z = Ofw[d * 17 + qw + 2];
            v.w = Ofw[d * 17 + qw + 3];
            *(float4*)&Oattn[((size_t)b * CCH + head * HD + d) * NSP + blockIdx.x * 64 + q4] = v;
        }
    }
}

// ---------------------------------------------------------------------------
extern "C" void kernel_launch(void* const* d_in, const int* in_sizes, int n_in,
                              void* d_out, int out_size, void* d_ws, size_t ws_size,
                              hipStream_t stream) {
    const float* x    = (const float*)d_in[0];
    const float* nw   = (const float*)d_in[1];
    const float* nb   = (const float*)d_in[2];
    const float* qkvw = (const float*)d_in[3];
    const float* qkvb = (const float*)d_in[4];
    const float* pw   = (const float*)d_in[5];
    const float* pb   = (const float*)d_in[6];
    float* out = (float*)d_out;

    // ws layout (40.1 MB total):
    //   [0, 2KB)                      gn partial sums
    //   [64KB, 64KB+16MB)             h fp32  (dead after gemm_qkv; reused as aout)
    //   [64KB+16MB, +8MB)             Qbf  bf16 packed [bh][qtile][q][d] (pre-scaled)
    //   [.. +8MB)                     Ktbf bf16 packed [bh][ktile][key][d^sw]
    //   [.. +8MB)                     Vbf  bf16 packed [bh][ktile][d][key^sw]
    char* ws = (char*)d_ws;
    float* sums = (float*)ws;
    float* h    = (float*)(ws + (1 << 16));
    unsigned short* Qbf  = (unsigned short*)(ws + (1 << 16) + ((size_t)16 << 20));
    unsigned short* Ktbf = Qbf  + (size_t)BATCH * NHEAD * NSP * HD;
    unsigned short* Vbf  = Ktbf + (size_t)BATCH * NHEAD * NSP * HD;
    float* aout = h;    // h dead once gemm_qkv has consumed it

    gn_partial<<<dim3(256), dim3(256), 0, stream>>>(x, sums);
    gn_apply<<<dim3(1024), dim3(256), 0, stream>>>(x, sums, nw, nb, h);
    gemm_qkv<<<dim3(NSP / 64, 12, BATCH), dim3(256), 0, stream>>>(qkvw, h, qkvb, Qbf, Ktbf, Vbf);
    flash_mfma<<<dim3(NSP / 64, NHEAD, BATCH), dim3(256), 0, stream>>>(Qbf, Ktbf, Vbf, aout);
    gemm1x1<<<dim3(NSP / 64, 4, BATCH), dim3(256), 0, stream>>>(pw, aout, pb, x, out, CCH);
}

// Round 8
// 292.391 us; speedup vs baseline: 9.9020x; 1.2778x over previous
//
#include <hip/hip_runtime.h>

// Problem constants (B=4, C=256, H=W=64, N=4096, groups=8, heads=4, hd=64)
#define BATCH 4
#define CCH   256
#define NSP   4096          // H*W
#define GRPSZ (32 * 4096)   // elements per group
#define NHEAD 4
#define HD    64

typedef __attribute__((ext_vector_type(8))) short short8;            // 8 bf16 MFMA A/B frag
typedef __attribute__((ext_vector_type(8))) unsigned short ushort8_t;
typedef __attribute__((ext_vector_type(4))) float f32x4;             // MFMA C/D frag

// round-to-nearest-even f32 -> bf16 bits
__device__ __forceinline__ unsigned short f2b(float f) {
    unsigned u = __builtin_bit_cast(unsigned, f);
    unsigned r = u + 0x7FFFu + ((u >> 16) & 1u);
    return (unsigned short)(r >> 16);
}

// ---------------------------------------------------------------------------
// GroupNorm pass 1: partial sums. grid = 32 groups * 8 chunks, block = 256.
// ---------------------------------------------------------------------------
__global__ __launch_bounds__(256) void gn_partial(const float* __restrict__ x,
                                                  float* __restrict__ sums) {
    int chunk = blockIdx.x & 7;
    int bg    = blockIdx.x >> 3;            // b*8 + g
    const float* base = x + (size_t)bg * GRPSZ + (size_t)chunk * (GRPSZ / 8);
    int t = threadIdx.x;
    float s = 0.f, ss = 0.f;
#pragma unroll
    for (int i = 0; i < 16; ++i) {
        float4 v = *(const float4*)&base[(t + i * 256) * 4];
        s  += v.x + v.y + v.z + v.w;
        ss += v.x * v.x + v.y * v.y + v.z * v.z + v.w * v.w;
    }
    __shared__ float rs[256], rss[256];
    rs[t] = s; rss[t] = ss;
    __syncthreads();
    for (int off = 128; off > 0; off >>= 1) {
        if (t < off) { rs[t] += rs[t + off]; rss[t] += rss[t + off]; }
        __syncthreads();
    }
    if (t == 0) {
        sums[blockIdx.x * 2]     = rs[0];
        sums[blockIdx.x * 2 + 1] = rss[0];
    }
}

// ---------------------------------------------------------------------------
// GroupNorm apply + transpose + bf16 cast, fused.
// x fp32 [b][c][n]  ->  hT bf16 [b][n][c].   grid (64 ntile, 4 ctile, B).
// ---------------------------------------------------------------------------
__global__ __launch_bounds__(256) void gn_pack(const float* __restrict__ x,
                                               const float* __restrict__ sums,
                                               const float* __restrict__ gw,
                                               const float* __restrict__ gb,
                                               unsigned short* __restrict__ hT) {
    __shared__ float LT[64][65];
    __shared__ float wcs[64], bcs[64];
    int b = blockIdx.z, c0 = blockIdx.y * 64, n0 = blockIdx.x * 64;
    int t = threadIdx.x;
    if (t < 64) {
        int c  = c0 + t;
        int bg = b * 8 + (c >> 5);
        float s = 0.f, ss = 0.f;
#pragma unroll
        for (int i = 0; i < 8; ++i) {
            s  += sums[(bg * 8 + i) * 2];
            ss += sums[(bg * 8 + i) * 2 + 1];
        }
        const float invn = 1.f / (float)GRPSZ;
        float mean = s * invn;
        float var  = ss * invn - mean * mean;
        float inv  = rsqrtf(var + 1e-5f);
        float wc = gw[c] * inv;
        wcs[t] = wc;
        bcs[t] = gb[c] - mean * wc;
    }
    __syncthreads();
    int cl4 = (t & 15) * 4, cr = t >> 4;
#pragma unroll
    for (int p = 0; p < 4; ++p) {
        int c = cr + p * 16;
        float4 v = *(const float4*)&x[(size_t)(b * 256 + c0 + c) * 4096 + n0 + cl4];
        float wc = wcs[c], bb = bcs[c];
        LT[c][cl4 + 0] = v.x * wc + bb;
        LT[c][cl4 + 1] = v.y * wc + bb;
        LT[c][cl4 + 2] = v.z * wc + bb;
        LT[c][cl4 + 3] = v.w * wc + bb;
    }
    __syncthreads();
#pragma unroll
    for (int p = 0; p < 2; ++p) {
        int n  = (t >> 3) + p * 32;
        int c8 = (t & 7) * 8;
        ushort8_t w;
#pragma unroll
        for (int i = 0; i < 8; ++i) w[i] = f2b(LT[c8 + i][n]);
        *(ushort8_t*)&hT[((size_t)b * 4096 + n0 + n) * 256 + c0 + c8] = w;
    }
}

// ---------------------------------------------------------------------------
// QKV GEMM, bf16 MFMA.  D[n][o] = sum_c hT[n][c] * W[o][c]  (+bias).
// grid (64 ntiles, 12 otiles, B), 256 thr = 4 waves; 64x64 tile, BK=64.
// Epilogue packs Q/K/V exactly in the layouts flash_mfma consumes:
//   Q: [q][d] *hd^-0.5;  K: [key][d ^ swK(key)];  V: [d][key ^ ((d&7)<<3)] (LDS transpose)
// ---------------------------------------------------------------------------
__global__ __launch_bounds__(256) void gemm_qkv(const float* __restrict__ W,
                                                const unsigned short* __restrict__ hT,
                                                const float* __restrict__ bias,
                                                unsigned short* __restrict__ Qbf,
                                                unsigned short* __restrict__ Ktbf,
                                                unsigned short* __restrict__ Vbf) {
    __shared__ unsigned short Wl[64 * 64];   // [o][k ^ ((o&7)<<3)]
    __shared__ unsigned short Hl[64 * 64];   // [n][k ^ ((n&7)<<3)]
    int b = blockIdx.z, o0 = blockIdx.y * 64, n0 = blockIdx.x * 64;
    int t = threadIdx.x, lane = t & 63, wid = t >> 6, g = lane >> 4, cl = lane & 15;
    f32x4 acc[4];
#pragma unroll
    for (int j = 0; j < 4; ++j) acc[j] = (f32x4){0.f, 0.f, 0.f, 0.f};
    int sr = t >> 2;            // staging row 0..63
    int sk = (t & 3) * 16;      // staging k offset
    int swr = (sr & 7) << 3;
    int swa = (cl & 7) << 3;
    for (int k0 = 0; k0 < 256; k0 += 64) {
        __syncthreads();
        {   // W fp32 -> bf16 LDS
            const float* wr = &W[(size_t)(o0 + sr) * 256 + k0 + sk];
            float4 w0 = *(const float4*)&wr[0],  w1 = *(const float4*)&wr[4];
            float4 w2 = *(const float4*)&wr[8],  w3 = *(const float4*)&wr[12];
            ushort8_t u0 = {f2b(w0.x), f2b(w0.y), f2b(w0.z), f2b(w0.w),
                            f2b(w1.x), f2b(w1.y), f2b(w1.z), f2b(w1.w)};
            ushort8_t u1 = {f2b(w2.x), f2b(w2.y), f2b(w2.z), f2b(w2.w),
                            f2b(w3.x), f2b(w3.y), f2b(w3.z), f2b(w3.w)};
            *(ushort8_t*)&Wl[sr * 64 + (sk ^ swr)]       = u0;
            *(ushort8_t*)&Wl[sr * 64 + ((sk + 8) ^ swr)] = u1;
        }
        {   // hT bf16 straight copy
            const ushort8_t* hr = (const ushort8_t*)&hT[((size_t)b * 4096 + n0 + sr) * 256 + k0 + sk];
            *(ushort8_t*)&Hl[sr * 64 + (sk ^ swr)]       = hr[0];
            *(ushort8_t*)&Hl[sr * 64 + ((sk + 8) ^ swr)] = hr[1];
        }
        __syncthreads();
#pragma unroll
        for (int ks = 0; ks < 2; ++ks) {
            short8 a = *(short8*)&Hl[(wid * 16 + cl) * 64 + ((ks * 32 + g * 8) ^ swa)];
#pragma unroll
            for (int j = 0; j < 4; ++j) {
                short8 bb = *(short8*)&Wl[(j * 16 + cl) * 64 + ((ks * 32 + g * 8) ^ swa)];
                acc[j] = __builtin_amdgcn_mfma_f32_16x16x32_bf16(a, bb, acc[j], 0, 0, 0);
            }
        }
    }
    // ---- pack epilogue. D: row(n) = wid*16+g*4+r, col(o) = j*16+cl.
    int sect = blockIdx.y >> 2, head = blockIdx.y & 3;
    size_t tilebase = (((size_t)b * NHEAD + head) * 64 + blockIdx.x) * 4096;
    int nrow = wid * 16 + g * 4;
    if (sect == 0) {
#pragma unroll
        for (int j = 0; j < 4; ++j) {
            float bi = bias[o0 + j * 16 + cl];
#pragma unroll
            for (int r = 0; r < 4; ++r)
                Qbf[tilebase + (size_t)(nrow + r) * 64 + j * 16 + cl] =
                    f2b((acc[j][r] + bi) * 0.125f);
        }
    } else if (sect == 1) {
#pragma unroll
        for (int j = 0; j < 4; ++j) {
            float bi = bias[o0 + j * 16 + cl];
#pragma unroll
            for (int r = 0; r < 4; ++r) {
                int key = nrow + r;
                int sw  = ((key ^ (key >> 3)) & 7) << 3;
                Ktbf[tilebase + (size_t)key * 64 + ((j * 16 + cl) ^ sw)] =
                    f2b(acc[j][r] + bi);
            }
        }
    } else {
        __syncthreads();                    // done reading Wl
        unsigned short* VL = Wl;            // reuse 8KB as [d][key^sw(d)]
#pragma unroll
        for (int j = 0; j < 4; ++j) {
            float bi = bias[o0 + j * 16 + cl];
            int d = j * 16 + cl;
#pragma unroll
            for (int r = 0; r < 4; ++r) {
                int key = nrow + r;
                VL[d * 64 + (key ^ ((d & 7) << 3))] = f2b(acc[j][r] + bi);
            }
        }
        __syncthreads();
        ushort8_t* dst = (ushort8_t*)&Vbf[tilebase];
        const ushort8_t* srcl = (const ushort8_t*)VL;
        dst[t]       = srcl[t];
        dst[t + 256] = srcl[t + 256];
    }
}

// ---------------------------------------------------------------------------
// Proj GEMM, bf16 MFMA.  Out[o][n] = sum_c W[o][c]*aT[n][c] + bias[o] + x.
// grid (64 ntiles, 4 otiles, B).  D: row=o, col=n.
// ---------------------------------------------------------------------------
__global__ __launch_bounds__(256) void gemm_proj(const float* __restrict__ W,
                                                 const unsigned short* __restrict__ aT,
                                                 const float* __restrict__ bias,
                                                 const float* __restrict__ x,
                                                 float* __restrict__ Out) {
    __shared__ unsigned short Wl[64 * 64];   // [o][k ^ sw(o)]
    __shared__ unsigned short Al[64 * 64];   // [n][k ^ sw(n)]
    int b = blockIdx.z, o0 = blockIdx.y * 64, n0 = blockIdx.x * 64;
    int t = threadIdx.x, lane = t & 63, wid = t >> 6, g = lane >> 4, cl = lane & 15;
    f32x4 acc[4];
#pragma unroll
    for (int j = 0; j < 4; ++j) acc[j] = (f32x4){0.f, 0.f, 0.f, 0.f};
    int sr = t >> 2, sk = (t & 3) * 16;
    int swr = (sr & 7) << 3;
    int swa = (cl & 7) << 3;
    for (int k0 = 0; k0 < 256; k0 += 64) {
        __syncthreads();
        {
            const float* wr = &W[(size_t)(o0 + sr) * 256 + k0 + sk];
            float4 w0 = *(const float4*)&wr[0],  w1 = *(const float4*)&wr[4];
            float4 w2 = *(const float4*)&wr[8],  w3 = *(const float4*)&wr[12];
            ushort8_t u0 = {f2b(w0.x), f2b(w0.y), f2b(w0.z), f2b(w0.w),
                            f2b(w1.x), f2b(w1.y), f2b(w1.z), f2b(w1.w)};
            ushort8_t u1 = {f2b(w2.x), f2b(w2.y), f2b(w2.z), f2b(w2.w),
                            f2b(w3.x), f2b(w3.y), f2b(w3.z), f2b(w3.w)};
            *(ushort8_t*)&Wl[sr * 64 + (sk ^ swr)]       = u0;
            *(ushort8_t*)&Wl[sr * 64 + ((sk + 8) ^ swr)] = u1;
        }
        {
            const ushort8_t* ar = (const ushort8_t*)&aT[((size_t)b * 4096 + n0 + sr) * 256 + k0 + sk];
            *(ushort8_t*)&Al[sr * 64 + (sk ^ swr)]       = ar[0];
            *(ushort8_t*)&Al[sr * 64 + ((sk + 8) ^ swr)] = ar[1];
        }
        __syncthreads();
#pragma unroll
        for (int ks = 0; ks < 2; ++ks) {
            short8 a = *(short8*)&Wl[(wid * 16 + cl) * 64 + ((ks * 32 + g * 8) ^ swa)];
#pragma unroll
            for (int j = 0; j < 4; ++j) {
                short8 bb = *(short8*)&Al[(j * 16 + cl) * 64 + ((ks * 32 + g * 8) ^ swa)];
                acc[j] = __builtin_amdgcn_mfma_f32_16x16x32_bf16(a, bb, acc[j], 0, 0, 0);
            }
        }
    }
    // D: row(o) = wid*16+g*4+r, col(n) = j*16+cl. Fused bias + residual.
    float bi[4];
#pragma unroll
    for (int r = 0; r < 4; ++r) bi[r] = bias[o0 + wid * 16 + g * 4 + r];
#pragma unroll
    for (int r = 0; r < 4; ++r) {
        int o = o0 + wid * 16 + g * 4 + r;
        size_t rowbase = ((size_t)b * 256 + o) * 4096 + n0;
#pragma unroll
        for (int j = 0; j < 4; ++j) {
            size_t idx = rowbase + j * 16 + cl;
            Out[idx] = acc[j][r] + bi[r] + x[idx];
        }
    }
}

// ---------------------------------------------------------------------------
// MFMA flash attention (pre-packed bf16 Q/K/V; fp32 accumulate).
// grid = (N/64, heads, B), block = 256 (4 waves x 16 queries).
// Core identical to R6; epilogue writes aout[q][c] bf16 directly (proj's
// B-operand layout) instead of the LDS-transpose fp32 path.
// ---------------------------------------------------------------------------
__global__ __launch_bounds__(256, 4) void flash_mfma(const unsigned short* __restrict__ Qbf,
                                                     const unsigned short* __restrict__ Ktbf,
                                                     const unsigned short* __restrict__ Vbf,
                                                     unsigned short* __restrict__ aoutbf) {
    __shared__ char smem[24576];
    unsigned short* Kt = (unsigned short*)smem;            // [64 key][64 d]  swizzled
    unsigned short* Vs = (unsigned short*)(smem + 8192);   // [64 d][64 key]  swizzled
    unsigned short* Pb = (unsigned short*)(smem + 16384);  // 4 waves x [16 q][64 k]

    const int t    = threadIdx.x;
    const int lane = t & 63;
    const int wid  = t >> 6;
    const int g    = lane >> 4;
    const int cl   = lane & 15;

    const int head = blockIdx.y, b = blockIdx.z;
    const int bh   = b * NHEAD + head;

    const unsigned short* Qt = Qbf + (((size_t)bh * 64 + blockIdx.x) * 4096);
    short8 qf[2];
    qf[0] = *(const short8*)&Qt[(wid * 16 + cl) * 64 + g * 8];
    qf[1] = *(const short8*)&Qt[(wid * 16 + cl) * 64 + 32 + g * 8];

    f32x4 o_acc[4];
#pragma unroll
    for (int ds = 0; ds < 4; ++ds) o_acc[ds] = (f32x4){0.f, 0.f, 0.f, 0.f};
    float m[4], l[4];
#pragma unroll
    for (int r = 0; r < 4; ++r) { m[r] = -1e30f; l[r] = 0.f; }

    for (int tile = 0; tile < 64; ++tile) {
        __syncthreads();
        {   // stage: linear 8 KB copies of pre-packed K-tile and V-tile
            const ushort8_t* kg = (const ushort8_t*)(Ktbf + (((size_t)bh * 64 + tile) * 4096));
            const ushort8_t* vg = (const ushort8_t*)(Vbf  + (((size_t)bh * 64 + tile) * 4096));
            ushort8_t* kl = (ushort8_t*)Kt;
            ushort8_t* vl = (ushort8_t*)Vs;
            kl[t]       = kg[t];
            kl[t + 256] = kg[t + 256];
            vl[t]       = vg[t];
            vl[t + 256] = vg[t + 256];
        }
        __syncthreads();

        // ---- S = Q^T K
        f32x4 accs[4];
#pragma unroll
        for (int s = 0; s < 4; ++s) {
            f32x4 a = (f32x4){0.f, 0.f, 0.f, 0.f};
            int row = s * 16 + cl;
            int sw  = ((row ^ (row >> 3)) & 7) << 3;
#pragma unroll
            for (int h = 0; h < 2; ++h) {
                short8 kf = *(short8*)&Kt[row * 64 + ((h * 32 + g * 8) ^ sw)];
                a = __builtin_amdgcn_mfma_f32_16x16x32_bf16(qf[h], kf, a, 0, 0, 0);
            }
            accs[s] = a;
        }

        // ---- online softmax (row r -> q = g*4+r; cols over 16 lanes)
        unsigned short pb16[4][4];
#pragma unroll
        for (int r = 0; r < 4; ++r) {
            float rm = fmaxf(fmaxf(accs[0][r], accs[1][r]), fmaxf(accs[2][r], accs[3][r]));
#pragma unroll
            for (int mask = 1; mask < 16; mask <<= 1)
                rm = fmaxf(rm, __shfl_xor(rm, mask));
            float mn   = fmaxf(m[r], rm);
            float corr = __expf(m[r] - mn);
            m[r] = mn;
            l[r] *= corr;
            o_acc[0][r] *= corr; o_acc[1][r] *= corr;
            o_acc[2][r] *= corr; o_acc[3][r] *= corr;
            float ps = 0.f;
#pragma unroll
            for (int s = 0; s < 4; ++s) {
                float p = __expf(accs[s][r] - mn);
                ps += p;
                pb16[r][s] = f2b(p);
            }
            l[r] += ps;
        }

        // ---- P -> per-wave LDS, then PV MFMAs
        unsigned short* Pw = Pb + wid * 16 * 64;
#pragma unroll
        for (int r = 0; r < 4; ++r) {
            int row = g * 4 + r;
#pragma unroll
            for (int s = 0; s < 4; ++s) {
                int col = s * 16 + cl;
                Pw[row * 64 + (col ^ ((row & 7) << 3))] = pb16[r][s];
            }
        }
        short8 pf[2];
#pragma unroll
        for (int h2 = 0; h2 < 2; ++h2)
            pf[h2] = *(short8*)&Pw[cl * 64 + ((h2 * 32 + g * 8) ^ ((cl & 7) << 3))];
#pragma unroll
        for (int ds = 0; ds < 4; ++ds) {
            int vrow = ds * 16 + cl;
#pragma unroll
            for (int h2 = 0; h2 < 2; ++h2) {
                short8 vf = *(short8*)&Vs[vrow * 64 + ((h2 * 32 + g * 8) ^ ((cl & 7) << 3))];
                o_acc[ds] = __builtin_amdgcn_mfma_f32_16x16x32_bf16(pf[h2], vf, o_acc[ds], 0, 0, 0);
            }
        }
    }

    // ---- finalize: reduce l, write aout[q][c] bf16 (lane-contiguous in c)
    float inv[4];
#pragma unroll
    for (int r = 0; r < 4; ++r) {
        float s = l[r];
#pragma unroll
        for (int mask = 1; mask < 16; mask <<= 1) s += __shfl_xor(s, mask);
        inv[r] = 1.f / s;
    }
    unsigned short* Ab = aoutbf + ((size_t)b * 4096 + blockIdx.x * 64 + wid * 16) * 256 + head * 64;
#pragma unroll
    for (int ds = 0; ds < 4; ++ds)
#pragma unroll
        for (int r = 0; r < 4; ++r)
            Ab[(size_t)(g * 4 + r) * 256 + ds * 16 + cl] = f2b(o_acc[ds][r] * inv[r]);
}

// ---------------------------------------------------------------------------
extern "C" void kernel_launch(void* const* d_in, const int* in_sizes, int n_in,
                              void* d_out, int out_size, void* d_ws, size_t ws_size,
                              hipStream_t stream) {
    const float* x    = (const float*)d_in[0];
    const float* nw   = (const float*)d_in[1];
    const float* nb   = (const float*)d_in[2];
    const float* qkvw = (const float*)d_in[3];
    const float* qkvb = (const float*)d_in[4];
    const float* pw   = (const float*)d_in[5];
    const float* pb   = (const float*)d_in[6];
    float* out = (float*)d_out;

    // ws layout (~40.1 MB):
    //   [0, 2KB)        gn partial sums
    //   [64KB, +8MB)    hT   bf16 [b][n][c]
    //   [+8MB each]     Qbf / Ktbf / Vbf  (packed per 64-tile, flash layouts)
    //   [+8MB]          aoutbf bf16 [b][q][c]
    char* ws = (char*)d_ws;
    float* sums = (float*)ws;
    unsigned short* hT     = (unsigned short*)(ws + (1 << 16));
    unsigned short* Qbf    = hT     + (size_t)BATCH * NSP * CCH;
    unsigned short* Ktbf   = Qbf    + (size_t)BATCH * NHEAD * NSP * HD;
    unsigned short* Vbf    = Ktbf   + (size_t)BATCH * NHEAD * NSP * HD;
    unsigned short* aoutbf = Vbf    + (size_t)BATCH * NHEAD * NSP * HD;

    gn_partial<<<dim3(256), dim3(256), 0, stream>>>(x, sums);
    gn_pack<<<dim3(64, 4, BATCH), dim3(256), 0, stream>>>(x, sums, nw, nb, hT);
    gemm_qkv<<<dim3(64, 12, BATCH), dim3(256), 0, stream>>>(qkvw, hT, qkvb, Qbf, Ktbf, Vbf);
    flash_mfma<<<dim3(64, NHEAD, BATCH), dim3(256), 0, stream>>>(Qbf, Ktbf, Vbf, aoutbf);
    gemm_proj<<<dim3(64, 4, BATCH), dim3(256), 0, stream>>>(pw, aoutbf, pb, x, out);
}

// Round 12
// 279.170 us; speedup vs baseline: 10.3710x; 1.0474x over previous
//
#include <hip/hip_runtime.h>
#include <hip/hip_bf16.h>

// Problem constants (B=4, C=256, H=W=64, N=4096, groups=8, heads=4, hd=64)
#define BATCH 4
#define CCH   256
#define NSP   4096          // H*W
#define GRPSZ (32 * 4096)   // elements per group
#define NHEAD 4
#define HD    64

typedef __attribute__((ext_vector_type(8))) short short8;            // 8 bf16 MFMA A/B frag
typedef __attribute__((ext_vector_type(8))) unsigned short ushort8_t;
typedef __attribute__((ext_vector_type(4))) float f32x4;             // MFMA C/D frag

// round-to-nearest-even f32 -> bf16 bits (bit-manip; known-good)
__device__ __forceinline__ unsigned short f2b(float f) {
    unsigned u = __builtin_bit_cast(unsigned, f);
    unsigned r = u + 0x7FFFu + ((u >> 16) & 1u);
    return (unsigned short)(r >> 16);
}
// RNE via HIP intrinsic (compiler emits native cvt) — used on the hot P path
__device__ __forceinline__ unsigned short b16p(float f) {
    __hip_bfloat16 h = __float2bfloat16(f);
    return __builtin_bit_cast(unsigned short, h);
}
// single-instruction 2^x
__device__ __forceinline__ float ex2(float x) {
    float r; asm("v_exp_f32 %0, %1" : "=v"(r) : "v"(x)); return r;
}

// ---------------------------------------------------------------------------
// GroupNorm pass 1: partial sums. grid = 32 groups * 8 chunks, block = 256.
// ---------------------------------------------------------------------------
__global__ __launch_bounds__(256) void gn_partial(const float* __restrict__ x,
                                                  float* __restrict__ sums) {
    int chunk = blockIdx.x & 7;
    int bg    = blockIdx.x >> 3;            // b*8 + g
    const float* base = x + (size_t)bg * GRPSZ + (size_t)chunk * (GRPSZ / 8);
    int t = threadIdx.x;
    float s = 0.f, ss = 0.f;
#pragma unroll
    for (int i = 0; i < 16; ++i) {
        float4 v = *(const float4*)&base[(t + i * 256) * 4];
        s  += v.x + v.y + v.z + v.w;
        ss += v.x * v.x + v.y * v.y + v.z * v.z + v.w * v.w;
    }
    __shared__ float rs[256], rss[256];
    rs[t] = s; rss[t] = ss;
    __syncthreads();
    for (int off = 128; off > 0; off >>= 1) {
        if (t < off) { rs[t] += rs[t + off]; rss[t] += rss[t + off]; }
        __syncthreads();
    }
    if (t == 0) {
        sums[blockIdx.x * 2]     = rs[0];
        sums[blockIdx.x * 2 + 1] = rss[0];
    }
}

// ---------------------------------------------------------------------------
// GroupNorm apply + transpose + bf16 cast, fused.
// x fp32 [b][c][n]  ->  hT bf16 [b][n][c].   grid (64 ntile, 4 ctile, B).
// ---------------------------------------------------------------------------
__global__ __launch_bounds__(256) void gn_pack(const float* __restrict__ x,
                                               const float* __restrict__ sums,
                                               const float* __restrict__ gw,
                                               const float* __restrict__ gb,
                                               unsigned short* __restrict__ hT) {
    __shared__ float LT[64][65];
    __shared__ float wcs[64], bcs[64];
    int b = blockIdx.z, c0 = blockIdx.y * 64, n0 = blockIdx.x * 64;
    int t = threadIdx.x;
    if (t < 64) {
        int c  = c0 + t;
        int bg = b * 8 + (c >> 5);
        float s = 0.f, ss = 0.f;
#pragma unroll
        for (int i = 0; i < 8; ++i) {
            s  += sums[(bg * 8 + i) * 2];
            ss += sums[(bg * 8 + i) * 2 + 1];
        }
        const float invn = 1.f / (float)GRPSZ;
        float mean = s * invn;
        float var  = ss * invn - mean * mean;
        float inv  = rsqrtf(var + 1e-5f);
        float wc = gw[c] * inv;
        wcs[t] = wc;
        bcs[t] = gb[c] - mean * wc;
    }
    __syncthreads();
    int cl4 = (t & 15) * 4, cr = t >> 4;
#pragma unroll
    for (int p = 0; p < 4; ++p) {
        int c = cr + p * 16;
        float4 v = *(const float4*)&x[(size_t)(b * 256 + c0 + c) * 4096 + n0 + cl4];
        float wc = wcs[c], bb = bcs[c];
        LT[c][cl4 + 0] = v.x * wc + bb;
        LT[c][cl4 + 1] = v.y * wc + bb;
        LT[c][cl4 + 2] = v.z * wc + bb;
        LT[c][cl4 + 3] = v.w * wc + bb;
    }
    __syncthreads();
#pragma unroll
    for (int p = 0; p < 2; ++p) {
        int n  = (t >> 3) + p * 32;
        int c8 = (t & 7) * 8;
        ushort8_t w;
#pragma unroll
        for (int i = 0; i < 8; ++i) w[i] = f2b(LT[c8 + i][n]);
        *(ushort8_t*)&hT[((size_t)b * 4096 + n0 + n) * 256 + c0 + c8] = w;
    }
}

// ---------------------------------------------------------------------------
// QKV GEMM, bf16 MFMA.  D[n][o] = sum_c hT[n][c] * W[o][c]  (+bias).
// Q scale folds hd^-0.5 * log2(e) so flash softmax runs in exp2 domain.
// ---------------------------------------------------------------------------
__global__ __launch_bounds__(256) void gemm_qkv(const float* __restrict__ W,
                                                const unsigned short* __restrict__ hT,
                                                const float* __restrict__ bias,
                                                unsigned short* __restrict__ Qbf,
                                                unsigned short* __restrict__ Ktbf,
                                                unsigned short* __restrict__ Vbf) {
    __shared__ unsigned short Wl[64 * 64];   // [o][k ^ ((o&7)<<3)]
    __shared__ unsigned short Hl[64 * 64];   // [n][k ^ ((n&7)<<3)]
    int b = blockIdx.z, o0 = blockIdx.y * 64, n0 = blockIdx.x * 64;
    int t = threadIdx.x, lane = t & 63, wid = t >> 6, g = lane >> 4, cl = lane & 15;
    f32x4 acc[4];
#pragma unroll
    for (int j = 0; j < 4; ++j) acc[j] = (f32x4){0.f, 0.f, 0.f, 0.f};
    int sr = t >> 2;            // staging row 0..63
    int sk = (t & 3) * 16;      // staging k offset
    int swr = (sr & 7) << 3;
    int swa = (cl & 7) << 3;
    for (int k0 = 0; k0 < 256; k0 += 64) {
        __syncthreads();
        {   // W fp32 -> bf16 LDS
            const float* wr = &W[(size_t)(o0 + sr) * 256 + k0 + sk];
            float4 w0 = *(const float4*)&wr[0],  w1 = *(const float4*)&wr[4];
            float4 w2 = *(const float4*)&wr[8],  w3 = *(const float4*)&wr[12];
            ushort8_t u0 = {f2b(w0.x), f2b(w0.y), f2b(w0.z), f2b(w0.w),
                            f2b(w1.x), f2b(w1.y), f2b(w1.z), f2b(w1.w)};
            ushort8_t u1 = {f2b(w2.x), f2b(w2.y), f2b(w2.z), f2b(w2.w),
                            f2b(w3.x), f2b(w3.y), f2b(w3.z), f2b(w3.w)};
            *(ushort8_t*)&Wl[sr * 64 + (sk ^ swr)]       = u0;
            *(ushort8_t*)&Wl[sr * 64 + ((sk + 8) ^ swr)] = u1;
        }
        {   // hT bf16 straight copy
            const ushort8_t* hr = (const ushort8_t*)&hT[((size_t)b * 4096 + n0 + sr) * 256 + k0 + sk];
            *(ushort8_t*)&Hl[sr * 64 + (sk ^ swr)]       = hr[0];
            *(ushort8_t*)&Hl[sr * 64 + ((sk + 8) ^ swr)] = hr[1];
        }
        __syncthreads();
#pragma unroll
        for (int ks = 0; ks < 2; ++ks) {
            short8 a = *(short8*)&Hl[(wid * 16 + cl) * 64 + ((ks * 32 + g * 8) ^ swa)];
#pragma unroll
            for (int j = 0; j < 4; ++j) {
                short8 bb = *(short8*)&Wl[(j * 16 + cl) * 64 + ((ks * 32 + g * 8) ^ swa)];
                acc[j] = __builtin_amdgcn_mfma_f32_16x16x32_bf16(a, bb, acc[j], 0, 0, 0);
            }
        }
    }
    // ---- pack epilogue. D: row(n) = wid*16+g*4+r, col(o) = j*16+cl.
    int sect = blockIdx.y >> 2, head = blockIdx.y & 3;
    size_t tilebase = (((size_t)b * NHEAD + head) * 64 + blockIdx.x) * 4096;
    int nrow = wid * 16 + g * 4;
    if (sect == 0) {
        const float qsc = 0.18033688011112042f;     // hd^-0.5 * log2(e)
#pragma unroll
        for (int j = 0; j < 4; ++j) {
            float bi = bias[o0 + j * 16 + cl];
#pragma unroll
            for (int r = 0; r < 4; ++r)
                Qbf[tilebase + (size_t)(nrow + r) * 64 + j * 16 + cl] =
                    f2b((acc[j][r] + bi) * qsc);
        }
    } else if (sect == 1) {
#pragma unroll
        for (int j = 0; j < 4; ++j) {
            float bi = bias[o0 + j * 16 + cl];
#pragma unroll
            for (int r = 0; r < 4; ++r) {
                int key = nrow + r;
                int sw  = ((key ^ (key >> 3)) & 7) << 3;
                Ktbf[tilebase + (size_t)key * 64 + ((j * 16 + cl) ^ sw)] =
                    f2b(acc[j][r] + bi);
            }
        }
    } else {
        __syncthreads();                    // done reading Wl
        unsigned short* VL = Wl;            // reuse 8KB as [d][key^sw(d)]
#pragma unroll
        for (int j = 0; j < 4; ++j) {
            float bi = bias[o0 + j * 16 + cl];
            int d = j * 16 + cl;
#pragma unroll
            for (int r = 0; r < 4; ++r) {
                int key = nrow + r;
                VL[d * 64 + (key ^ ((d & 7) << 3))] = f2b(acc[j][r] + bi);
            }
        }
        __syncthreads();
        ushort8_t* dst = (ushort8_t*)&Vbf[tilebase];
        const ushort8_t* srcl = (const ushort8_t*)VL;
        dst[t]       = srcl[t];
        dst[t + 256] = srcl[t + 256];
    }
}

// ---------------------------------------------------------------------------
// Proj GEMM, bf16 MFMA.  Out[o][n] = sum_c W[o][c]*aT[n][c] + bias[o] + x.
// ---------------------------------------------------------------------------
__global__ __launch_bounds__(256) void gemm_proj(const float* __restrict__ W,
                                                 const unsigned short* __restrict__ aT,
                                                 const float* __restrict__ bias,
                                                 const float* __restrict__ x,
                                                 float* __restrict__ Out) {
    __shared__ unsigned short Wl[64 * 64];   // [o][k ^ sw(o)]
    __shared__ unsigned short Al[64 * 64];   // [n][k ^ sw(n)]
    int b = blockIdx.z, o0 = blockIdx.y * 64, n0 = blockIdx.x * 64;
    int t = threadIdx.x, lane = t & 63, wid = t >> 6, g = lane >> 4, cl = lane & 15;
    f32x4 acc[4];
#pragma unroll
    for (int j = 0; j < 4; ++j) acc[j] = (f32x4){0.f, 0.f, 0.f, 0.f};
    int sr = t >> 2, sk = (t & 3) * 16;
    int swr = (sr & 7) << 3;
    int swa = (cl & 7) << 3;
    for (int k0 = 0; k0 < 256; k0 += 64) {
        __syncthreads();
        {
            const float* wr = &W[(size_t)(o0 + sr) * 256 + k0 + sk];
            float4 w0 = *(const float4*)&wr[0],  w1 = *(const float4*)&wr[4];
            float4 w2 = *(const float4*)&wr[8],  w3 = *(const float4*)&wr[12];
            ushort8_t u0 = {f2b(w0.x), f2b(w0.y), f2b(w0.z), f2b(w0.w),
                            f2b(w1.x), f2b(w1.y), f2b(w1.z), f2b(w1.w)};
            ushort8_t u1 = {f2b(w2.x), f2b(w2.y), f2b(w2.z), f2b(w2.w),
                            f2b(w3.x), f2b(w3.y), f2b(w3.z), f2b(w3.w)};
            *(ushort8_t*)&Wl[sr * 64 + (sk ^ swr)]       = u0;
            *(ushort8_t*)&Wl[sr * 64 + ((sk + 8) ^ swr)] = u1;
        }
        {
            const ushort8_t* ar = (const ushort8_t*)&aT[((size_t)b * 4096 + n0 + sr) * 256 + k0 + sk];
            *(ushort8_t*)&Al[sr * 64 + (sk ^ swr)]       = ar[0];
            *(ushort8_t*)&Al[sr * 64 + ((sk + 8) ^ swr)] = ar[1];
        }
        __syncthreads();
#pragma unroll
        for (int ks = 0; ks < 2; ++ks) {
            short8 a = *(short8*)&Wl[(wid * 16 + cl) * 64 + ((ks * 32 + g * 8) ^ swa)];
#pragma unroll
            for (int j = 0; j < 4; ++j) {
                short8 bb = *(short8*)&Al[(j * 16 + cl) * 64 + ((ks * 32 + g * 8) ^ swa)];
                acc[j] = __builtin_amdgcn_mfma_f32_16x16x32_bf16(a, bb, acc[j], 0, 0, 0);
            }
        }
    }
    float bi[4];
#pragma unroll
    for (int r = 0; r < 4; ++r) bi[r] = bias[o0 + wid * 16 + g * 4 + r];
#pragma unroll
    for (int r = 0; r < 4; ++r) {
        int o = o0 + wid * 16 + g * 4 + r;
        size_t rowbase = ((size_t)b * 256 + o) * 4096 + n0;
#pragma unroll
        for (int j = 0; j < 4; ++j) {
            size_t idx = rowbase + j * 16 + cl;
            Out[idx] = acc[j][r] + bi[r] + x[idx];
        }
    }
}

// ---------------------------------------------------------------------------
// MFMA flash attention v3: exp2-domain softmax, defer-max, double-buffered
// pipelined staging (1 barrier/tile, global loads issued before compute).
// grid = (N/64, heads, B), block = 256 (4 waves x 16 queries).
// LDS 40KB via direct __shared__ arrays (no pointer-array init — gfx950
// rejects addrspacecast static initializers). 4 blocks/CU = 160KB exact.
// ---------------------------------------------------------------------------
__global__ __launch_bounds__(256, 4) void flash_mfma(const unsigned short* __restrict__ Qbf,
                                                     const unsigned short* __restrict__ Ktbf,
                                                     const unsigned short* __restrict__ Vbf,
                                                     unsigned short* __restrict__ aoutbf) {
    __shared__ unsigned short Kbuf[2][4096];   // [64 key][64 d] swizzled, x2
    __shared__ unsigned short Vbuf[2][4096];   // [64 d][64 key] swizzled, x2
    __shared__ unsigned short Pbuf[4096];      // 4 waves x [16 q][64 k]

    const int t    = threadIdx.x;
    const int lane = t & 63;
    const int wid  = t >> 6;
    const int g    = lane >> 4;
    const int cl   = lane & 15;

    const int head = blockIdx.y, b = blockIdx.z;
    const int bh   = b * NHEAD + head;

    const unsigned short* Qt = Qbf + (((size_t)bh * 64 + blockIdx.x) * 4096);
    short8 qf[2];
    qf[0] = *(const short8*)&Qt[(wid * 16 + cl) * 64 + g * 8];
    qf[1] = *(const short8*)&Qt[(wid * 16 + cl) * 64 + 32 + g * 8];

    const ushort8_t* kg = (const ushort8_t*)(Ktbf + (size_t)bh * 64 * 4096);
    const ushort8_t* vg = (const ushort8_t*)(Vbf  + (size_t)bh * 64 * 4096);

    f32x4 o_acc[4];
#pragma unroll
    for (int ds = 0; ds < 4; ++ds) o_acc[ds] = (f32x4){0.f, 0.f, 0.f, 0.f};
    float m[4], l[4];
#pragma unroll
    for (int r = 0; r < 4; ++r) { m[r] = -1e30f; l[r] = 0.f; }

    // prologue: stage tile 0
    ushort8_t kr0 = kg[t], kr1 = kg[t + 256];
    ushort8_t vr0 = vg[t], vr1 = vg[t + 256];
    ((ushort8_t*)&Kbuf[0][0])[t] = kr0;  ((ushort8_t*)&Kbuf[0][0])[t + 256] = kr1;
    ((ushort8_t*)&Vbuf[0][0])[t] = vr0;  ((ushort8_t*)&Vbuf[0][0])[t + 256] = vr1;
    __syncthreads();

    for (int tile = 0; tile < 64; ++tile) {
        const int cur = tile & 1;
        const unsigned short* KT = &Kbuf[cur][0];
        const unsigned short* VS = &Vbuf[cur][0];
        // issue next tile's global loads (latency hides under compute)
        if (tile < 63) {
            const ushort8_t* kn = kg + (size_t)(tile + 1) * 512;
            const ushort8_t* vn = vg + (size_t)(tile + 1) * 512;
            kr0 = kn[t]; kr1 = kn[t + 256];
            vr0 = vn[t]; vr1 = vn[t + 256];
        }

        // ---- S = Q^T K
        f32x4 accs[4];
#pragma unroll
        for (int s = 0; s < 4; ++s) {
            f32x4 a = (f32x4){0.f, 0.f, 0.f, 0.f};
            int row = s * 16 + cl;
            int sw  = ((row ^ (row >> 3)) & 7) << 3;
#pragma unroll
            for (int h = 0; h < 2; ++h) {
                short8 kf = *(const short8*)&KT[row * 64 + ((h * 32 + g * 8) ^ sw)];
                a = __builtin_amdgcn_mfma_f32_16x16x32_bf16(qf[h], kf, a, 0, 0, 0);
            }
            accs[s] = a;
        }

        // ---- online softmax, exp2 domain, defer-max (THR=8 -> P <= 256)
        float nm[4];
        int need = 0;
#pragma unroll
        for (int r = 0; r < 4; ++r) {
            float rm = fmaxf(fmaxf(accs[0][r], accs[1][r]), fmaxf(accs[2][r], accs[3][r]));
#pragma unroll
            for (int mask = 1; mask < 16; mask <<= 1)
                rm = fmaxf(rm, __shfl_xor(rm, mask));
            nm[r] = fmaxf(m[r], rm);
            need |= (rm > m[r] + 8.f) ? 1 : 0;
        }
        if (__any(need)) {
#pragma unroll
            for (int r = 0; r < 4; ++r) {
                float corr = ex2(m[r] - nm[r]);
                l[r] *= corr;
                o_acc[0][r] *= corr; o_acc[1][r] *= corr;
                o_acc[2][r] *= corr; o_acc[3][r] *= corr;
                m[r] = nm[r];
            }
        }
        unsigned short pb16[4][4];
#pragma unroll
        for (int r = 0; r < 4; ++r) {
            float ps = 0.f;
#pragma unroll
            for (int s = 0; s < 4; ++s) {
                float p = ex2(accs[s][r] - m[r]);
                ps += p;
                pb16[r][s] = b16p(p);
            }
            l[r] += ps;
        }

        // ---- P -> per-wave LDS, then PV MFMAs
        unsigned short* Pw = &Pbuf[wid * 16 * 64];
#pragma unroll
        for (int r = 0; r < 4; ++r) {
            int row = g * 4 + r;
#pragma unroll
            for (int s = 0; s < 4; ++s) {
                int col = s * 16 + cl;
                Pw[row * 64 + (col ^ ((row & 7) << 3))] = pb16[r][s];
            }
        }
        short8 pf[2];
#pragma unroll
        for (int h2 = 0; h2 < 2; ++h2)
            pf[h2] = *(const short8*)&Pw[cl * 64 + ((h2 * 32 + g * 8) ^ ((cl & 7) << 3))];
#pragma unroll
        for (int ds = 0; ds < 4; ++ds) {
            int vrow = ds * 16 + cl;
#pragma unroll
            for (int h2 = 0; h2 < 2; ++h2) {
                short8 vf = *(const short8*)&VS[vrow * 64 + ((h2 * 32 + g * 8) ^ ((cl & 7) << 3))];
                o_acc[ds] = __builtin_amdgcn_mfma_f32_16x16x32_bf16(pf[h2], vf, o_acc[ds], 0, 0, 0);
            }
        }

        // commit next tile into the other buffer, single barrier per tile
        if (tile < 63) {
            ushort8_t* KN = (ushort8_t*)&Kbuf[cur ^ 1][0];
            ushort8_t* VN = (ushort8_t*)&Vbuf[cur ^ 1][0];
            KN[t] = kr0;  KN[t + 256] = kr1;
            VN[t] = vr0;  VN[t + 256] = vr1;
        }
        __syncthreads();
    }

    // ---- finalize: reduce l, write aout[q][c] bf16
    float inv[4];
#pragma unroll
    for (int r = 0; r < 4; ++r) {
        float s = l[r];
#pragma unroll
        for (int mask = 1; mask < 16; mask <<= 1) s += __shfl_xor(s, mask);
        inv[r] = 1.f / s;
    }
    unsigned short* Ab = aoutbf + ((size_t)b * 4096 + blockIdx.x * 64 + wid * 16) * 256 + head * 64;
#pragma unroll
    for (int ds = 0; ds < 4; ++ds)
#pragma unroll
        for (int r = 0; r < 4; ++r)
            Ab[(size_t)(g * 4 + r) * 256 + ds * 16 + cl] = f2b(o_acc[ds][r] * inv[r]);
}

// ---------------------------------------------------------------------------
extern "C" void kernel_launch(void* const* d_in, const int* in_sizes, int n_in,
                              void* d_out, int out_size, void* d_ws, size_t ws_size,
                              hipStream_t stream) {
    const float* x    = (const float*)d_in[0];
    const float* nw   = (const float*)d_in[1];
    const float* nb   = (const float*)d_in[2];
    const float* qkvw = (const float*)d_in[3];
    const float* qkvb = (const float*)d_in[4];
    const float* pw   = (const float*)d_in[5];
    const float* pb   = (const float*)d_in[6];
    float* out = (float*)d_out;

    // ws layout (~40.1 MB):
    //   [0, 2KB)        gn partial sums
    //   [64KB, +8MB)    hT   bf16 [b][n][c]
    //   [+8MB each]     Qbf / Ktbf / Vbf  (packed per 64-tile, flash layouts)
    //   [+8MB]          aoutbf bf16 [b][q][c]
    char* ws = (char*)d_ws;
    float* sums = (float*)ws;
    unsigned short* hT     = (unsigned short*)(ws + (1 << 16));
    unsigned short* Qbf    = hT     + (size_t)BATCH * NSP * CCH;
    unsigned short* Ktbf   = Qbf    + (size_t)BATCH * NHEAD * NSP * HD;
    unsigned short* Vbf    = Ktbf   + (size_t)BATCH * NHEAD * NSP * HD;
    unsigned short* aoutbf = Vbf    + (size_t)BATCH * NHEAD * NSP * HD;

    gn_partial<<<dim3(256), dim3(256), 0, stream>>>(x, sums);
    gn_pack<<<dim3(64, 4, BATCH), dim3(256), 0, stream>>>(x, sums, nw, nb, hT);
    gemm_qkv<<<dim3(64, 12, BATCH), dim3(256), 0, stream>>>(qkvw, hT, qkvb, Qbf, Ktbf, Vbf);
    flash_mfma<<<dim3(64, NHEAD, BATCH), dim3(256), 0, stream>>>(Qbf, Ktbf, Vbf, aoutbf);
    gemm_proj<<<dim3(64, 4, BATCH), dim3(256), 0, stream>>>(pw, aoutbf, pb, x, out);
}